// Round 18
// baseline (822.022 us; speedup 1.0000x reference)
//
#include <hip/hip_runtime.h>
#include <math.h>

// ---------------------------------------------------------------------------
// AlexNet forward, batch 128.
// Round 18: conv2 tiling geometry — 4 output rows/block (was 7): halo [8][32],
// LDS 40KB -> 4 blocks/CU (was 56.3KB -> 2), exact 7x7x16=784 tile cover (no
// padding waste), acc[2][4]. Inner loop/weight path IDENTICAL to the measured
// 208us v4 (structure changes all failed; this is geometry only).
//
// Workspace layout (bytes):
//   X2 hi/lo [0,25.69M)   conv1out fp32 [25.69M,132.15M)  (dead after pool1cvt)
//   wt2/3/4/5 hi/lo [25.69M,35.47M)  (written after conv1out dead)
//   Y2 hi/lo [36M,113.07M)   X3 hi/lo [113.1M,129.71M)
//   Y3 [36M,69.23M)  Y4 [70M,92.15M)  Y5 [93M,115.15M)
//   P3 [0,4.72M)  FC1 [5M,7.1M)  FC2 [8M,10.1M)  LOG [11M)  PART [40M,73.6M)
// ---------------------------------------------------------------------------

typedef __attribute__((ext_vector_type(4))) float  f32x4;
typedef __attribute__((ext_vector_type(8))) short  bf16x8;

#define OFF_C1O      25690112ull
#define OFF_X2H      0ull
#define OFF_X2L      12845056ull
#define OFF_WT2H     25690112ull
#define OFF_WT2L     26304512ull
#define OFF_WT3H     26918912ull
#define OFF_WT3L     28246016ull
#define OFF_WT4H     29573120ull
#define OFF_WT4L     31342592ull
#define OFF_WT5H     33112064ull
#define OFF_WT5L     34291712ull
#define OFF_Y2H      36000000ull
#define OFF_Y2L      74535168ull
#define OFF_X3H      113100000ull
#define OFF_X3L      121406688ull
#define OFF_Y3H      36000000ull
#define OFF_Y3L      52613376ull
#define OFF_Y4H      70000000ull
#define OFF_Y4L      81075584ull
#define OFF_Y5H      93000000ull
#define OFF_Y5L      104075584ull
#define OFF_P3       0ull
#define OFF_FC1      5000000ull
#define OFF_FC2      8000000ull
#define OFF_LOG      11000000ull
#define OFF_PART     40000000ull

__device__ inline void bf16split(float v, unsigned short& h, unsigned short& l) {
  unsigned u = __builtin_bit_cast(unsigned, v);
  unsigned hb = (u + 0x7fffu + ((u >> 16) & 1u)) >> 16;        // RNE to bf16
  h = (unsigned short)hb;
  float hf = __builtin_bit_cast(float, hb << 16);
  float r = v - hf;
  unsigned u2 = __builtin_bit_cast(unsigned, r);
  l = (unsigned short)((u2 + 0x7fffu + ((u2 >> 16) & 1u)) >> 16);
}
// trunc-hi split: hi exact truncation, lo = RNE(v - hi)
__device__ inline void bf16split_fast(float v, unsigned short& h, unsigned short& l) {
  unsigned u = __builtin_bit_cast(unsigned, v);
  h = (unsigned short)(u >> 16);
  float r = v - __builtin_bit_cast(float, u & 0xFFFF0000u);
  unsigned u2 = __builtin_bit_cast(unsigned, r);
  l = (unsigned short)((u2 + 0x7fffu + ((u2 >> 16) & 1u)) >> 16);
}
__device__ inline float bf2f(unsigned short h) {
  return __builtin_bit_cast(float, ((unsigned)h) << 16);
}

// ---------------- conv1: x[128,3,224,224] -> y1[128,64,57,57], k3 s4 p2, relu
__global__ __launch_bounds__(256) void conv1_kernel(
    const float* __restrict__ x, const float* __restrict__ w,
    const float* __restrict__ bias, float* __restrict__ out) {
  const int b = blockIdx.y;
  const int s = blockIdx.x * 256 + threadIdx.x;
  if (s >= 57 * 57) return;
  const int oh = s / 57, ow = s % 57;
  float iv[27];
#pragma unroll
  for (int ci = 0; ci < 3; ++ci)
#pragma unroll
    for (int kh = 0; kh < 3; ++kh)
#pragma unroll
      for (int kw = 0; kw < 3; ++kw) {
        const int ih = oh * 4 - 2 + kh;
        const int iw = ow * 4 - 2 + kw;
        float v = 0.f;
        if (ih >= 0 && ih < 224 && iw >= 0 && iw < 224)
          v = x[(((size_t)b * 3 + ci) * 224 + ih) * 224 + iw];
        iv[ci * 9 + kh * 3 + kw] = v;
      }
  for (int co = 0; co < 64; ++co) {
    float a = bias[co];
#pragma unroll
    for (int p = 0; p < 27; ++p) a = fmaf(w[co * 27 + p], iv[p], a);
    out[((size_t)b * 64 + co) * 3249 + s] = fmaxf(a, 0.f);
  }
}

// ---------------- fused pool1 + bf16 hi/lo convert
__global__ __launch_bounds__(256) void pool1cvt_kernel(
    const float* __restrict__ in, unsigned short* __restrict__ xh,
    unsigned short* __restrict__ xl) {
  const int tid = blockIdx.x * 256 + threadIdx.x;
  if (tid >= 128 * 784) return;
  const int b = tid / 784, s = tid % 784;
  const int oh = s / 28, ow = s % 28;
  const float* base = in + (size_t)b * 64 * 3249 + (size_t)(oh * 2) * 57 + ow * 2;
  for (int cg = 0; cg < 16; ++cg) {
    unsigned short h[4], l[4];
#pragma unroll
    for (int j = 0; j < 4; ++j) {
      const float* p = base + (size_t)(cg * 4 + j) * 3249;
      float m = -INFINITY;
#pragma unroll
      for (int kh = 0; kh < 3; ++kh)
#pragma unroll
        for (int kw = 0; kw < 3; ++kw) m = fmaxf(m, p[kh * 57 + kw]);
      bf16split(m, h[j], l[j]);
    }
    const size_t g = ((size_t)b * 784 + s) * 64 + cg * 4;
    *reinterpret_cast<uint2*>(xh + g) =
        make_uint2((unsigned)h[0] | ((unsigned)h[1] << 16),
                   (unsigned)h[2] | ((unsigned)h[3] << 16));
    *reinterpret_cast<uint2*>(xl + g) =
        make_uint2((unsigned)l[0] | ((unsigned)l[1] << 16),
                   (unsigned)l[2] | ((unsigned)l[3] << 16));
  }
}

// ---------------- weight transform to MFMA-fragment layout:
// w[co][ci][P] fp32 -> wh/wl [cotile][p][cc][fr:16co][32ci] bf16
__global__ void wtrans_hl_kernel(const float* __restrict__ w,
                                 unsigned short* __restrict__ wh,
                                 unsigned short* __restrict__ wl,
                                 int C_in, int P, int C_out) {
  const int ncc = C_in >> 5;
  const int total = C_out * P * C_in;
  for (int e = blockIdx.x * blockDim.x + threadIdx.x; e < total;
       e += gridDim.x * blockDim.x) {
    const int ci_in = e & 31;
    int t1 = e >> 5;
    const int fr = t1 & 15;
    int t2 = t1 >> 4;
    const int cc = t2 % ncc;
    int t3 = t2 / ncc;
    const int p = t3 % P;
    const int ct = t3 / P;
    const int co = ct * 16 + fr;
    const int ci = cc * 32 + ci_in;
    const float v = w[((size_t)co * C_in + ci) * P + p];
    unsigned short h, l;
    bf16split(v, h, l);
    wh[e] = h; wl[e] = l;
  }
}

// ---------------- conv2 MFMA v5: 4-row groups, 40KB LDS -> 4 blocks/CU.
// Block = (image, 4-row group rg<7, 64-co group). Wave wv owns tiles {wv, wv+4}
// of 7 n-tiles (7x16 = 112 = 4x28 exact). Inner loop identical to v4.
__global__ __launch_bounds__(256, 2) void conv2_mfma_kernel(
    const unsigned short* __restrict__ xh, const unsigned short* __restrict__ xl,
    const unsigned short* __restrict__ wh, const unsigned short* __restrict__ wl,
    const float* __restrict__ bias,
    unsigned short* __restrict__ yh, unsigned short* __restrict__ yl) {
  __shared__ unsigned short xt_h[256 * 40];   // 8 halo rows x 32 cols x 40ch-pad
  __shared__ unsigned short xt_l[256 * 40];
  const int t = threadIdx.x;
  const int lane = t & 63, wv = t >> 6;
  const int b = blockIdx.x;
  const int rg = blockIdx.y;                  // output rows rg*4 .. rg*4+3
  const int cg = blockIdx.z;
  const int fr = lane & 15, fq = lane >> 4;
  const int k0 = fq * 8;
  const int frag = fr * 32 + k0;   // lane offset inside a [16co][32ci] frag

  int bofs[2];
  bool act[2];
#pragma unroll
  for (int ti = 0; ti < 2; ++ti) {
    const int tile = ti * 4 + wv;
    act[ti] = (tile <= 6);
    int n = tile * 16 + fr;
    if (tile > 6) n = 111;
    const int r = n / 28, c = n % 28;
    bofs[ti] = (r * 32 + c) * 40 + k0;
  }

  f32x4 acc[2][4];
#pragma unroll
  for (int i = 0; i < 2; ++i)
#pragma unroll
    for (int j = 0; j < 4; ++j) acc[i][j] = (f32x4){0.f, 0.f, 0.f, 0.f};

  for (int cc = 0; cc < 2; ++cc) {
    __syncthreads();
    for (int e = t; e < 1024; e += 256) {
      const int sp = e >> 2, kg = e & 3;
      const int hr = sp >> 5, hc = sp & 31;
      const int ih = rg * 4 + hr - 2, ic = hc - 2;
      uint4 vh = make_uint4(0, 0, 0, 0), vl = make_uint4(0, 0, 0, 0);
      if (ih >= 0 && ih < 28 && ic >= 0 && ic < 28) {
        const size_t g = ((size_t)b * 784 + ih * 28 + ic) * 64 + cc * 32 + kg * 8;
        vh = *reinterpret_cast<const uint4*>(xh + g);
        vl = *reinterpret_cast<const uint4*>(xl + g);
      }
      *reinterpret_cast<uint4*>(xt_h + sp * 40 + kg * 8) = vh;
      *reinterpret_cast<uint4*>(xt_l + sp * 40 + kg * 8) = vl;
    }
    __syncthreads();
#pragma unroll 5
    for (int p = 0; p < 25; ++p) {
      bf16x8 a_h[4], a_l[4];
#pragma unroll
      for (int cot = 0; cot < 4; ++cot) {
        // wt2 layout: [cotile=cg*4+cot][p][cc][16co][32ci]
        const size_t wg = ((((size_t)(cg * 4 + cot) * 25 + p) * 2 + cc) << 9) + frag;
        a_h[cot] = __builtin_bit_cast(bf16x8, *reinterpret_cast<const uint4*>(wh + wg));
        a_l[cot] = __builtin_bit_cast(bf16x8, *reinterpret_cast<const uint4*>(wl + wg));
      }
      const int kh = p / 5, kw = p % 5;
      const int poff = (kh * 32 + kw) * 40;
      bf16x8 bh[2], bl[2];
#pragma unroll
      for (int ti = 0; ti < 2; ++ti) {
        if (act[ti]) {
          bh[ti] = __builtin_bit_cast(bf16x8,
              *reinterpret_cast<const uint4*>(xt_h + bofs[ti] + poff));
          bl[ti] = __builtin_bit_cast(bf16x8,
              *reinterpret_cast<const uint4*>(xt_l + bofs[ti] + poff));
        }
      }
      // product-major phases: hh, h*lo_x, lo_w*h
#pragma unroll
      for (int ti = 0; ti < 2; ++ti) if (act[ti])
#pragma unroll
        for (int cot = 0; cot < 4; ++cot)
          acc[ti][cot] = __builtin_amdgcn_mfma_f32_16x16x32_bf16(a_h[cot], bh[ti], acc[ti][cot], 0, 0, 0);
#pragma unroll
      for (int ti = 0; ti < 2; ++ti) if (act[ti])
#pragma unroll
        for (int cot = 0; cot < 4; ++cot)
          acc[ti][cot] = __builtin_amdgcn_mfma_f32_16x16x32_bf16(a_h[cot], bl[ti], acc[ti][cot], 0, 0, 0);
#pragma unroll
      for (int ti = 0; ti < 2; ++ti) if (act[ti])
#pragma unroll
        for (int cot = 0; cot < 4; ++cot)
          acc[ti][cot] = __builtin_amdgcn_mfma_f32_16x16x32_bf16(a_l[cot], bh[ti], acc[ti][cot], 0, 0, 0);
    }
  }
#pragma unroll
  for (int cot = 0; cot < 4; ++cot) {
    const int co = cg * 64 + cot * 16 + fq * 4;
    const float4 bi = *reinterpret_cast<const float4*>(bias + co);
    const float bia[4] = {bi.x, bi.y, bi.z, bi.w};
#pragma unroll
    for (int ti = 0; ti < 2; ++ti) {
      const int tile = ti * 4 + wv;
      if (tile > 6) continue;
      const int n = tile * 16 + fr;
      const int oh = rg * 4 + n / 28, ow = n % 28;
      unsigned short h[4], l[4];
#pragma unroll
      for (int r = 0; r < 4; ++r) {
        const float v = fmaxf(acc[ti][cot][r] + bia[r], 0.f);
        bf16split(v, h[r], l[r]);
      }
      const size_t g = ((size_t)b * 784 + oh * 28 + ow) * 192 + co;
      *reinterpret_cast<uint2*>(yh + g) =
          make_uint2((unsigned)h[0] | ((unsigned)h[1] << 16),
                     (unsigned)h[2] | ((unsigned)h[3] << 16));
      *reinterpret_cast<uint2*>(yl + g) =
          make_uint2((unsigned)l[0] | ((unsigned)l[1] << 16),
                     (unsigned)l[2] | ((unsigned)l[3] << 16));
    }
  }
}

// ---------------- pool2 (vectorized): Y2 hi/lo [b][784][192] -> X3 [b][169][192]
__global__ __launch_bounds__(256) void pool2_hl_kernel(
    const unsigned short* __restrict__ yh, const unsigned short* __restrict__ yl,
    unsigned short* __restrict__ xh, unsigned short* __restrict__ xl) {
  const int tid = blockIdx.x * 256 + threadIdx.x;
  if (tid >= 128 * 169 * 48) return;
  const int c4 = tid % 48;
  const int r = tid / 48;
  const int s = r % 169;
  const int b = r / 169;
  const int oh = s / 13, ow = s % 13;
  float m[4] = {-INFINITY, -INFINITY, -INFINITY, -INFINITY};
#pragma unroll
  for (int kh = 0; kh < 3; ++kh) {
#pragma unroll
    for (int kw = 0; kw < 3; ++kw) {
      const int si = (oh * 2 + kh) * 28 + (ow * 2 + kw);
      const size_t g = ((size_t)b * 784 + si) * 192 + c4 * 4;
      const uint2 vh = *reinterpret_cast<const uint2*>(yh + g);
      const uint2 vl = *reinterpret_cast<const uint2*>(yl + g);
      const unsigned hw[2] = {vh.x, vh.y}, lw[2] = {vl.x, vl.y};
#pragma unroll
      for (int j = 0; j < 4; ++j) {
        const float v = bf2f((unsigned short)(hw[j >> 1] >> ((j & 1) * 16))) +
                        bf2f((unsigned short)(lw[j >> 1] >> ((j & 1) * 16)));
        m[j] = fmaxf(m[j], v);
      }
    }
  }
  unsigned short h[4], l[4];
#pragma unroll
  for (int j = 0; j < 4; ++j) bf16split(m[j], h[j], l[j]);
  const size_t gd = ((size_t)b * 169 + s) * 192 + c4 * 4;
  *reinterpret_cast<uint2*>(xh + gd) =
      make_uint2((unsigned)h[0] | ((unsigned)h[1] << 16),
                 (unsigned)h[2] | ((unsigned)h[3] << 16));
  *reinterpret_cast<uint2*>(xl + gd) =
      make_uint2((unsigned)l[0] | ((unsigned)l[1] << 16),
                 (unsigned)l[2] | ((unsigned)l[3] << 16));
}

// ---------------- conv3/4/5 MFMA: coalesced frag weights
__global__ __launch_bounds__(256, 4) void conv13_mfma_kernel(
    const unsigned short* __restrict__ xh, const unsigned short* __restrict__ xl,
    const unsigned short* __restrict__ wh, const unsigned short* __restrict__ wl,
    const float* __restrict__ bias,
    unsigned short* __restrict__ yh, unsigned short* __restrict__ yl,
    int C_in, int C_out) {
  __shared__ unsigned short xt_h[225 * 40];
  __shared__ unsigned short xt_l[225 * 40];
  const int t = threadIdx.x;
  const int lane = t & 63;
  const int wv = t >> 6;
  const int b = blockIdx.x;
  const int co0 = blockIdx.y * 64 + wv * 16;
  const int ctile = blockIdx.y * 4 + wv;
  const int fr = lane & 15;
  const int fq = lane >> 4;
  const int k0 = fq * 8;
  const int frag = fr * 32 + k0;

  int bofs[11];
#pragma unroll
  for (int nt = 0; nt < 11; ++nt) {
    int n = nt * 16 + fr;
    if (n > 168) n = 168;
    const int oh = n / 13, ow = n % 13;
    bofs[nt] = (oh * 15 + ow) * 40 + k0;
  }

  f32x4 acc[11];
#pragma unroll
  for (int nt = 0; nt < 11; ++nt) acc[nt] = (f32x4){0.f, 0.f, 0.f, 0.f};

  const int ncc = C_in >> 5;
  for (int cc = 0; cc < ncc; ++cc) {
    __syncthreads();
    for (int e = t; e < 900; e += 256) {
      const int sp = e >> 2, kg = e & 3;
      const int r = sp / 15, c = sp % 15;
      const int ir = r - 1, ic = c - 1;
      uint4 vh = make_uint4(0, 0, 0, 0), vl = make_uint4(0, 0, 0, 0);
      if (ir >= 0 && ir < 13 && ic >= 0 && ic < 13) {
        const size_t g = ((size_t)b * 169 + ir * 13 + ic) * C_in + cc * 32 + kg * 8;
        vh = *reinterpret_cast<const uint4*>(xh + g);
        vl = *reinterpret_cast<const uint4*>(xl + g);
      }
      *reinterpret_cast<uint4*>(xt_h + sp * 40 + kg * 8) = vh;
      *reinterpret_cast<uint4*>(xt_l + sp * 40 + kg * 8) = vl;
    }
    __syncthreads();
#pragma unroll
    for (int p = 0; p < 9; ++p) {
      // wt layout: [ctile][p][cc][16co][32ci]
      const size_t wg = ((((size_t)ctile * 9 + p) * ncc + cc) << 9) + frag;
      const bf16x8 ca_h = __builtin_bit_cast(bf16x8, *reinterpret_cast<const uint4*>(wh + wg));
      const bf16x8 ca_l = __builtin_bit_cast(bf16x8, *reinterpret_cast<const uint4*>(wl + wg));
      const int poff = ((p / 3) * 15 + (p % 3)) * 40;
#pragma unroll
      for (int q = 0; q < 3; ++q) {
        const int nq = (q < 2) ? 4 : 3;
        bf16x8 bh[4], bl[4];
#pragma unroll
        for (int i = 0; i < 4; ++i) {
          if (i < nq) {
            bh[i] = __builtin_bit_cast(bf16x8,
                *reinterpret_cast<const uint4*>(xt_h + bofs[q * 4 + i] + poff));
            bl[i] = __builtin_bit_cast(bf16x8,
                *reinterpret_cast<const uint4*>(xt_l + bofs[q * 4 + i] + poff));
          }
        }
#pragma unroll
        for (int i = 0; i < 4; ++i) if (i < nq)
          acc[q * 4 + i] = __builtin_amdgcn_mfma_f32_16x16x32_bf16(ca_h, bh[i], acc[q * 4 + i], 0, 0, 0);
#pragma unroll
        for (int i = 0; i < 4; ++i) if (i < nq)
          acc[q * 4 + i] = __builtin_amdgcn_mfma_f32_16x16x32_bf16(ca_h, bl[i], acc[q * 4 + i], 0, 0, 0);
#pragma unroll
        for (int i = 0; i < 4; ++i) if (i < nq)
          acc[q * 4 + i] = __builtin_amdgcn_mfma_f32_16x16x32_bf16(ca_l, bh[i], acc[q * 4 + i], 0, 0, 0);
      }
    }
  }
  const int co_w = co0 + fq * 4;
  const float4 bi = *reinterpret_cast<const float4*>(bias + co_w);
  const float bia[4] = {bi.x, bi.y, bi.z, bi.w};
#pragma unroll
  for (int nt = 0; nt < 11; ++nt) {
    const int n = nt * 16 + fr;
    if (n > 168) continue;
    unsigned short h[4], l[4];
#pragma unroll
    for (int r = 0; r < 4; ++r) {
      float v = fmaxf(acc[nt][r] + bia[r], 0.f);
      bf16split(v, h[r], l[r]);
    }
    const size_t g = ((size_t)b * 169 + n) * C_out + co_w;
    *reinterpret_cast<uint2*>(yh + g) =
        make_uint2((unsigned)h[0] | ((unsigned)h[1] << 16),
                   (unsigned)h[2] | ((unsigned)h[3] << 16));
    *reinterpret_cast<uint2*>(yl + g) =
        make_uint2((unsigned)l[0] | ((unsigned)l[1] << 16),
                   (unsigned)l[2] | ((unsigned)l[3] << 16));
  }
}

// ---------------- pool3: Y5 hi/lo [b][169][256] -> fp32 [b][256][6][6]
__global__ __launch_bounds__(256) void pool3_hl_kernel(
    const unsigned short* __restrict__ yh, const unsigned short* __restrict__ yl,
    float* __restrict__ out) {
  const int b = blockIdx.x;
  const int s2 = blockIdx.y;
  const int c = threadIdx.x;
  const int oh = s2 / 6, ow = s2 % 6;
  float m = -INFINITY;
#pragma unroll
  for (int kh = 0; kh < 3; ++kh)
#pragma unroll
    for (int kw = 0; kw < 3; ++kw) {
      const int si = (oh * 2 + kh) * 13 + (ow * 2 + kw);
      const size_t g = ((size_t)b * 169 + si) * 256 + c;
      m = fmaxf(m, bf2f(yh[g]) + bf2f(yl[g]));
    }
  out[((size_t)b * 256 + c) * 36 + s2] = m;
}

// ---------------- fc1/fc2 MFMA: reg-split weights, nt-pair product-major
__global__ __launch_bounds__(256, 2) void fc_mfma_kernel(
    const float* __restrict__ act, const float* __restrict__ Wm,
    float* __restrict__ part, int K, int kchunk, int Cout) {
  __shared__ unsigned short ah[128 * 40];
  __shared__ unsigned short al[128 * 40];
  const int t = threadIdx.x;
  const int lane = t & 63, wv = t >> 6;
  const int m0 = blockIdx.x * 128 + wv * 32;
  const int kb = blockIdx.y * kchunk;
  const int fr = lane & 15, fq = lane >> 4;

  f32x4 acc[2][8];
#pragma unroll
  for (int i = 0; i < 2; ++i)
#pragma unroll
    for (int j = 0; j < 8; ++j) acc[i][j] = (f32x4){0.f, 0.f, 0.f, 0.f};

  for (int kc = kb; kc < kb + kchunk; kc += 32) {
    __syncthreads();
#pragma unroll
    for (int i = 0; i < 4; ++i) {
      const int u = t + i * 256;
      const int n = u >> 3, j = u & 7;
      const float4 v = *reinterpret_cast<const float4*>(act + (size_t)n * K + kc + j * 4);
      const float vv[4] = {v.x, v.y, v.z, v.w};
      unsigned short h[4], l[4];
#pragma unroll
      for (int q = 0; q < 4; ++q) bf16split_fast(vv[q], h[q], l[q]);
      *reinterpret_cast<uint2*>(ah + n * 40 + j * 4) =
          make_uint2((unsigned)h[0] | ((unsigned)h[1] << 16),
                     (unsigned)h[2] | ((unsigned)h[3] << 16));
      *reinterpret_cast<uint2*>(al + n * 40 + j * 4) =
          make_uint2((unsigned)l[0] | ((unsigned)l[1] << 16),
                     (unsigned)l[2] | ((unsigned)l[3] << 16));
    }
    __syncthreads();
    bf16x8 a_h[2], a_l[2];
#pragma unroll
    for (int mt = 0; mt < 2; ++mt) {
      const float* wp = Wm + (size_t)(m0 + mt * 16 + fr) * K + kc + fq * 8;
      const float4 w0 = *reinterpret_cast<const float4*>(wp);
      const float4 w1 = *reinterpret_cast<const float4*>(wp + 4);
      const float ws[8] = {w0.x, w0.y, w0.z, w0.w, w1.x, w1.y, w1.z, w1.w};
#pragma unroll
      for (int q = 0; q < 8; ++q) {
        unsigned short h, l;
        bf16split_fast(ws[q], h, l);
        a_h[mt][q] = (short)h;
        a_l[mt][q] = (short)l;
      }
    }
#pragma unroll
    for (int np = 0; np < 4; ++np) {
      bf16x8 bh[2], bl[2];
#pragma unroll
      for (int i = 0; i < 2; ++i) {
        const int nt = np * 2 + i;
        bh[i] = __builtin_bit_cast(bf16x8,
            *reinterpret_cast<const uint4*>(ah + (nt * 16 + fr) * 40 + fq * 8));
        bl[i] = __builtin_bit_cast(bf16x8,
            *reinterpret_cast<const uint4*>(al + (nt * 16 + fr) * 40 + fq * 8));
      }
#pragma unroll
      for (int i = 0; i < 2; ++i)
#pragma unroll
        for (int mt = 0; mt < 2; ++mt)
          acc[mt][np * 2 + i] = __builtin_amdgcn_mfma_f32_16x16x32_bf16(a_h[mt], bh[i], acc[mt][np * 2 + i], 0, 0, 0);
#pragma unroll
      for (int i = 0; i < 2; ++i)
#pragma unroll
        for (int mt = 0; mt < 2; ++mt)
          acc[mt][np * 2 + i] = __builtin_amdgcn_mfma_f32_16x16x32_bf16(a_h[mt], bl[i], acc[mt][np * 2 + i], 0, 0, 0);
#pragma unroll
      for (int i = 0; i < 2; ++i)
#pragma unroll
        for (int mt = 0; mt < 2; ++mt)
          acc[mt][np * 2 + i] = __builtin_amdgcn_mfma_f32_16x16x32_bf16(a_l[mt], bh[i], acc[mt][np * 2 + i], 0, 0, 0);
    }
  }
  const size_t base = (size_t)blockIdx.y * Cout * 128;
#pragma unroll
  for (int mt = 0; mt < 2; ++mt) {
#pragma unroll
    for (int nt = 0; nt < 8; ++nt) {
#pragma unroll
      for (int r = 0; r < 4; ++r) {
        const int m = m0 + mt * 16 + fq * 4 + r;
        const int n = nt * 16 + fr;
        part[base + (size_t)m * 128 + n] = acc[mt][nt][r];
      }
    }
  }
}

// ---------------- fc reduce: sum KS partials, +bias, relu, transpose to [n][Cout]
__global__ __launch_bounds__(256) void fc_reduce_kernel(
    const float* __restrict__ part, const float* __restrict__ bias,
    float* __restrict__ out, int Cout, int KS, int relu) {
  const int g = blockIdx.x * 256 + threadIdx.x;
  if (g >= Cout * 128) return;
  const int n = g & 127, m = g >> 7;
  float s = 0.f;
  for (int ks = 0; ks < KS; ++ks)
    s += part[(size_t)ks * Cout * 128 + (size_t)m * 128 + n];
  s += bias[m];
  if (relu) s = fmaxf(s, 0.f);
  out[(size_t)n * Cout + m] = s;
}

// ---------------- fc3: logits[128,10]
__global__ __launch_bounds__(256) void fc3_kernel(
    const float* __restrict__ A, const float* __restrict__ W,
    const float* __restrict__ bias, float* __restrict__ out) {
  __shared__ float red[256];
  const int b = blockIdx.x;
  const int t = threadIdx.x;
  float acc[10];
#pragma unroll
  for (int n = 0; n < 10; ++n) acc[n] = 0.f;
  const float* a = A + (size_t)b * 4096;
  for (int k = t; k < 4096; k += 256) {
    const float av = a[k];
#pragma unroll
    for (int n = 0; n < 10; ++n) acc[n] = fmaf(av, W[n * 4096 + k], acc[n]);
  }
  for (int n = 0; n < 10; ++n) {
    red[t] = acc[n];
    __syncthreads();
    for (int off = 128; off > 0; off >>= 1) {
      if (t < off) red[t] += red[t + off];
      __syncthreads();
    }
    if (t == 0) out[b * 10 + n] = red[0] + bias[n];
    __syncthreads();
  }
}

// ---------------- post
__global__ void post_kernel(const float* __restrict__ logits,
                            const float* __restrict__ unif,
                            const float* __restrict__ noise,
                            float* __restrict__ out) {
  const int b = blockIdx.x * blockDim.x + threadIdx.x;
  if (b >= 128) return;
  float lg[10];
#pragma unroll
  for (int j = 0; j < 10; ++j) lg[j] = logits[b * 10 + j];
  float m = lg[0];
  int idx = 0;
#pragma unroll
  for (int j = 1; j < 10; ++j) {
    if (lg[j] > m) { m = lg[j]; idx = j; }
  }
  float v[10];
#pragma unroll
  for (int j = 0; j < 10; ++j)
    v[j] = ((j == idx) ? lg[j] : unif[b * 10 + j] * m) + noise[b * 10 + j];
  float mx = v[0];
#pragma unroll
  for (int j = 1; j < 10; ++j) mx = fmaxf(mx, v[j]);
  float sum = 0.f;
#pragma unroll
  for (int j = 0; j < 10; ++j) { v[j] = expf(v[j] - mx); sum += v[j]; }
  const float inv = 1.f / sum;
#pragma unroll
  for (int j = 0; j < 10; ++j) out[b * 10 + j] = v[j] * inv;
}

// ---------------------------------------------------------------------------
extern "C" void kernel_launch(void* const* d_in, const int* in_sizes, int n_in,
                              void* d_out, int out_size, void* d_ws, size_t ws_size,
                              hipStream_t stream) {
  const float* x     = (const float*)d_in[0];
  const float* w1    = (const float*)d_in[1];
  const float* b1    = (const float*)d_in[2];
  const float* w2    = (const float*)d_in[3];
  const float* b2    = (const float*)d_in[4];
  const float* w3    = (const float*)d_in[5];
  const float* b3    = (const float*)d_in[6];
  const float* w4    = (const float*)d_in[7];
  const float* b4    = (const float*)d_in[8];
  const float* w5    = (const float*)d_in[9];
  const float* b5    = (const float*)d_in[10];
  const float* fc1_w = (const float*)d_in[11];
  const float* fc1_b = (const float*)d_in[12];
  const float* fc2_w = (const float*)d_in[13];
  const float* fc2_b = (const float*)d_in[14];
  const float* fc3_w = (const float*)d_in[15];
  const float* fc3_b = (const float*)d_in[16];
  const float* unif  = (const float*)d_in[17];
  const float* noise = (const float*)d_in[18];
  float* out = (float*)d_out;

  char* W = (char*)d_ws;
#define FP(off) ((float*)(W + (off)))
#define US(off) ((unsigned short*)(W + (off)))

  // conv1 -> fp32 [128,64,57,57] at OFF_C1O
  conv1_kernel<<<dim3(13, 128), 256, 0, stream>>>(x, w1, b1, FP(OFF_C1O));
  // fused pool1+convert -> X2 hi/lo [b][784][64]
  pool1cvt_kernel<<<392, 256, 0, stream>>>(FP(OFF_C1O), US(OFF_X2H), US(OFF_X2L));
  // weight transforms (fragment layout)
  wtrans_hl_kernel<<<512, 256, 0, stream>>>(w2, US(OFF_WT2H), US(OFF_WT2L), 64, 25, 192);
  wtrans_hl_kernel<<<512, 256, 0, stream>>>(w3, US(OFF_WT3H), US(OFF_WT3L), 192, 9, 384);
  wtrans_hl_kernel<<<512, 256, 0, stream>>>(w4, US(OFF_WT4H), US(OFF_WT4L), 384, 9, 256);
  wtrans_hl_kernel<<<512, 256, 0, stream>>>(w5, US(OFF_WT5H), US(OFF_WT5L), 256, 9, 256);
  // conv2 -> Y2 hi/lo [b][784][192]  (4-row groups: grid y=7)
  conv2_mfma_kernel<<<dim3(128, 7, 3), 256, 0, stream>>>(
      US(OFF_X2H), US(OFF_X2L), US(OFF_WT2H), US(OFF_WT2L), b2,
      US(OFF_Y2H), US(OFF_Y2L));
  // pool2 -> X3 hi/lo [b][169][192]
  pool2_hl_kernel<<<4056, 256, 0, stream>>>(
      US(OFF_Y2H), US(OFF_Y2L), US(OFF_X3H), US(OFF_X3L));
  // conv3 -> Y3 [b][169][384]
  conv13_mfma_kernel<<<dim3(128, 6), 256, 0, stream>>>(
      US(OFF_X3H), US(OFF_X3L), US(OFF_WT3H), US(OFF_WT3L), b3,
      US(OFF_Y3H), US(OFF_Y3L), 192, 384);
  // conv4 -> Y4 [b][169][256]
  conv13_mfma_kernel<<<dim3(128, 4), 256, 0, stream>>>(
      US(OFF_Y3H), US(OFF_Y3L), US(OFF_WT4H), US(OFF_WT4L), b4,
      US(OFF_Y4H), US(OFF_Y4L), 384, 256);
  // conv5 -> Y5 [b][169][256]
  conv13_mfma_kernel<<<dim3(128, 4), 256, 0, stream>>>(
      US(OFF_Y4H), US(OFF_Y4L), US(OFF_WT5H), US(OFF_WT5L), b5,
      US(OFF_Y5H), US(OFF_Y5L), 256, 256);
  // pool3 -> P3 fp32 [128][9216]
  pool3_hl_kernel<<<dim3(128, 36), 256, 0, stream>>>(US(OFF_Y5H), US(OFF_Y5L), FP(OFF_P3));
  // fc1/fc2
  fc_mfma_kernel<<<dim3(32, 16), 256, 0, stream>>>(FP(OFF_P3), fc1_w, FP(OFF_PART), 9216, 576, 4096);
  fc_reduce_kernel<<<2048, 256, 0, stream>>>(FP(OFF_PART), fc1_b, FP(OFF_FC1), 4096, 16, 1);
  fc_mfma_kernel<<<dim3(32, 16), 256, 0, stream>>>(FP(OFF_FC1), fc2_w, FP(OFF_PART), 4096, 256, 4096);
  fc_reduce_kernel<<<2048, 256, 0, stream>>>(FP(OFF_PART), fc2_b, FP(OFF_FC2), 4096, 16, 1);
  // fc3 + post
  fc3_kernel<<<128, 256, 0, stream>>>(FP(OFF_FC2), fc3_w, fc3_b, FP(OFF_LOG));
  post_kernel<<<1, 128, 0, stream>>>(FP(OFF_LOG), unif, noise, out);
}

// Round 19
// 732.621 us; speedup vs baseline: 1.1220x; 1.1220x over previous
//
#include <hip/hip_runtime.h>
#include <math.h>

// ---------------------------------------------------------------------------
// AlexNet forward, batch 128.
// Round 19: conv2 v6 = v4 (208us, coalesced frag weights, 7-row groups) +
// register prefetch of next-p weight fragments. Rationale: with the coalesced
// layout the weight path is latency-bound (not BW like rounds 6-7 when
// prefetch was neutral); v5/512thr showed perf tracks MFMA:weight-load ratio.
// Everything else = round-17 state (740us).
//
// Workspace layout (bytes):
//   X2 hi/lo [0,25.69M)   conv1out fp32 [25.69M,132.15M)  (dead after pool1cvt)
//   wt2/3/4/5 hi/lo [25.69M,35.47M)  (written after conv1out dead)
//   Y2 hi/lo [36M,113.07M)   X3 hi/lo [113.1M,129.71M)
//   Y3 [36M,69.23M)  Y4 [70M,92.15M)  Y5 [93M,115.15M)
//   P3 [0,4.72M)  FC1 [5M,7.1M)  FC2 [8M,10.1M)  LOG [11M)  PART [40M,73.6M)
// ---------------------------------------------------------------------------

typedef __attribute__((ext_vector_type(4))) float  f32x4;
typedef __attribute__((ext_vector_type(8))) short  bf16x8;

#define OFF_C1O      25690112ull
#define OFF_X2H      0ull
#define OFF_X2L      12845056ull
#define OFF_WT2H     25690112ull
#define OFF_WT2L     26304512ull
#define OFF_WT3H     26918912ull
#define OFF_WT3L     28246016ull
#define OFF_WT4H     29573120ull
#define OFF_WT4L     31342592ull
#define OFF_WT5H     33112064ull
#define OFF_WT5L     34291712ull
#define OFF_Y2H      36000000ull
#define OFF_Y2L      74535168ull
#define OFF_X3H      113100000ull
#define OFF_X3L      121406688ull
#define OFF_Y3H      36000000ull
#define OFF_Y3L      52613376ull
#define OFF_Y4H      70000000ull
#define OFF_Y4L      81075584ull
#define OFF_Y5H      93000000ull
#define OFF_Y5L      104075584ull
#define OFF_P3       0ull
#define OFF_FC1      5000000ull
#define OFF_FC2      8000000ull
#define OFF_LOG      11000000ull
#define OFF_PART     40000000ull

__device__ inline void bf16split(float v, unsigned short& h, unsigned short& l) {
  unsigned u = __builtin_bit_cast(unsigned, v);
  unsigned hb = (u + 0x7fffu + ((u >> 16) & 1u)) >> 16;        // RNE to bf16
  h = (unsigned short)hb;
  float hf = __builtin_bit_cast(float, hb << 16);
  float r = v - hf;
  unsigned u2 = __builtin_bit_cast(unsigned, r);
  l = (unsigned short)((u2 + 0x7fffu + ((u2 >> 16) & 1u)) >> 16);
}
// trunc-hi split: hi exact truncation, lo = RNE(v - hi)
__device__ inline void bf16split_fast(float v, unsigned short& h, unsigned short& l) {
  unsigned u = __builtin_bit_cast(unsigned, v);
  h = (unsigned short)(u >> 16);
  float r = v - __builtin_bit_cast(float, u & 0xFFFF0000u);
  unsigned u2 = __builtin_bit_cast(unsigned, r);
  l = (unsigned short)((u2 + 0x7fffu + ((u2 >> 16) & 1u)) >> 16);
}
__device__ inline float bf2f(unsigned short h) {
  return __builtin_bit_cast(float, ((unsigned)h) << 16);
}

// ---------------- conv1: x[128,3,224,224] -> y1[128,64,57,57], k3 s4 p2, relu
__global__ __launch_bounds__(256) void conv1_kernel(
    const float* __restrict__ x, const float* __restrict__ w,
    const float* __restrict__ bias, float* __restrict__ out) {
  const int b = blockIdx.y;
  const int s = blockIdx.x * 256 + threadIdx.x;
  if (s >= 57 * 57) return;
  const int oh = s / 57, ow = s % 57;
  float iv[27];
#pragma unroll
  for (int ci = 0; ci < 3; ++ci)
#pragma unroll
    for (int kh = 0; kh < 3; ++kh)
#pragma unroll
      for (int kw = 0; kw < 3; ++kw) {
        const int ih = oh * 4 - 2 + kh;
        const int iw = ow * 4 - 2 + kw;
        float v = 0.f;
        if (ih >= 0 && ih < 224 && iw >= 0 && iw < 224)
          v = x[(((size_t)b * 3 + ci) * 224 + ih) * 224 + iw];
        iv[ci * 9 + kh * 3 + kw] = v;
      }
  for (int co = 0; co < 64; ++co) {
    float a = bias[co];
#pragma unroll
    for (int p = 0; p < 27; ++p) a = fmaf(w[co * 27 + p], iv[p], a);
    out[((size_t)b * 64 + co) * 3249 + s] = fmaxf(a, 0.f);
  }
}

// ---------------- fused pool1 + bf16 hi/lo convert
__global__ __launch_bounds__(256) void pool1cvt_kernel(
    const float* __restrict__ in, unsigned short* __restrict__ xh,
    unsigned short* __restrict__ xl) {
  const int tid = blockIdx.x * 256 + threadIdx.x;
  if (tid >= 128 * 784) return;
  const int b = tid / 784, s = tid % 784;
  const int oh = s / 28, ow = s % 28;
  const float* base = in + (size_t)b * 64 * 3249 + (size_t)(oh * 2) * 57 + ow * 2;
  for (int cg = 0; cg < 16; ++cg) {
    unsigned short h[4], l[4];
#pragma unroll
    for (int j = 0; j < 4; ++j) {
      const float* p = base + (size_t)(cg * 4 + j) * 3249;
      float m = -INFINITY;
#pragma unroll
      for (int kh = 0; kh < 3; ++kh)
#pragma unroll
        for (int kw = 0; kw < 3; ++kw) m = fmaxf(m, p[kh * 57 + kw]);
      bf16split(m, h[j], l[j]);
    }
    const size_t g = ((size_t)b * 784 + s) * 64 + cg * 4;
    *reinterpret_cast<uint2*>(xh + g) =
        make_uint2((unsigned)h[0] | ((unsigned)h[1] << 16),
                   (unsigned)h[2] | ((unsigned)h[3] << 16));
    *reinterpret_cast<uint2*>(xl + g) =
        make_uint2((unsigned)l[0] | ((unsigned)l[1] << 16),
                   (unsigned)l[2] | ((unsigned)l[3] << 16));
  }
}

// ---------------- weight transform to MFMA-fragment layout:
// w[co][ci][P] fp32 -> wh/wl [cotile][p][cc][fr:16co][32ci] bf16
__global__ void wtrans_hl_kernel(const float* __restrict__ w,
                                 unsigned short* __restrict__ wh,
                                 unsigned short* __restrict__ wl,
                                 int C_in, int P, int C_out) {
  const int ncc = C_in >> 5;
  const int total = C_out * P * C_in;
  for (int e = blockIdx.x * blockDim.x + threadIdx.x; e < total;
       e += gridDim.x * blockDim.x) {
    const int ci_in = e & 31;
    int t1 = e >> 5;
    const int fr = t1 & 15;
    int t2 = t1 >> 4;
    const int cc = t2 % ncc;
    int t3 = t2 / ncc;
    const int p = t3 % P;
    const int ct = t3 / P;
    const int co = ct * 16 + fr;
    const int ci = cc * 32 + ci_in;
    const float v = w[((size_t)co * C_in + ci) * P + p];
    unsigned short h, l;
    bf16split(v, h, l);
    wh[e] = h; wl[e] = l;
  }
}

// ---------------- conv2 MFMA v6: v4 + register prefetch of next-p weights.
// 256 thr / 4 waves, coalesced frag weights, single-pass hi+lo LDS staging.
__global__ __launch_bounds__(256, 2) void conv2_mfma_kernel(
    const unsigned short* __restrict__ xh, const unsigned short* __restrict__ xl,
    const unsigned short* __restrict__ wh, const unsigned short* __restrict__ wl,
    const float* __restrict__ bias,
    unsigned short* __restrict__ yh, unsigned short* __restrict__ yl) {
  __shared__ unsigned short xt_h[352 * 40];
  __shared__ unsigned short xt_l[352 * 40];
  const int t = threadIdx.x;
  const int lane = t & 63, wv = t >> 6;
  const int b = blockIdx.x;
  const int rg = blockIdx.y;
  const int cg = blockIdx.z;
  const int fr = lane & 15, fq = lane >> 4;
  const int k0 = fq * 8;
  const int frag = fr * 32 + k0;   // lane offset inside a [16co][32ci] frag

  int bofs[4];
  bool act[4];
#pragma unroll
  for (int ti = 0; ti < 4; ++ti) {
    const int tile = ti * 4 + wv;
    act[ti] = (tile <= 12);
    int n = tile * 16 + fr;
    if (tile > 12 || n > 195) n = 195;
    const int r = n / 28, c = n % 28;
    bofs[ti] = (r * 32 + c) * 40 + k0;
  }

  f32x4 acc[4][4];
#pragma unroll
  for (int i = 0; i < 4; ++i)
#pragma unroll
    for (int j = 0; j < 4; ++j) acc[i][j] = (f32x4){0.f, 0.f, 0.f, 0.f};

  for (int cc = 0; cc < 2; ++cc) {
    __syncthreads();
    for (int e = t; e < 1408; e += 256) {
      const int sp = e >> 2, kg = e & 3;
      const int hr = sp >> 5, hc = sp & 31;
      const int ih = rg * 7 + hr - 2, ic = hc - 2;
      uint4 vh = make_uint4(0, 0, 0, 0), vl = make_uint4(0, 0, 0, 0);
      if (ih >= 0 && ih < 28 && ic >= 0 && ic < 28) {
        const size_t g = ((size_t)b * 784 + ih * 28 + ic) * 64 + cc * 32 + kg * 8;
        vh = *reinterpret_cast<const uint4*>(xh + g);
        vl = *reinterpret_cast<const uint4*>(xl + g);
      }
      *reinterpret_cast<uint4*>(xt_h + sp * 40 + kg * 8) = vh;
      *reinterpret_cast<uint4*>(xt_l + sp * 40 + kg * 8) = vl;
    }
    __syncthreads();

    // prologue: load p=0 weight fragments
    bf16x8 cur_h[4], cur_l[4];
#pragma unroll
    for (int cot = 0; cot < 4; ++cot) {
      const size_t wg = ((((size_t)(cg * 4 + cot) * 25 + 0) * 2 + cc) << 9) + frag;
      cur_h[cot] = __builtin_bit_cast(bf16x8, *reinterpret_cast<const uint4*>(wh + wg));
      cur_l[cot] = __builtin_bit_cast(bf16x8, *reinterpret_cast<const uint4*>(wl + wg));
    }
#pragma unroll 5
    for (int p = 0; p < 25; ++p) {
      // prefetch p+1 weights (issue before MFMAs; consumed next iteration)
      bf16x8 nxt_h[4], nxt_l[4];
      if (p < 24) {
#pragma unroll
        for (int cot = 0; cot < 4; ++cot) {
          const size_t wg = ((((size_t)(cg * 4 + cot) * 25 + (p + 1)) * 2 + cc) << 9) + frag;
          nxt_h[cot] = __builtin_bit_cast(bf16x8, *reinterpret_cast<const uint4*>(wh + wg));
          nxt_l[cot] = __builtin_bit_cast(bf16x8, *reinterpret_cast<const uint4*>(wl + wg));
        }
      }
      const int kh = p / 5, kw = p % 5;
      const int poff = (kh * 32 + kw) * 40;
      bf16x8 bh[4], bl[4];
#pragma unroll
      for (int ti = 0; ti < 4; ++ti) {
        if (act[ti]) {
          bh[ti] = __builtin_bit_cast(bf16x8,
              *reinterpret_cast<const uint4*>(xt_h + bofs[ti] + poff));
          bl[ti] = __builtin_bit_cast(bf16x8,
              *reinterpret_cast<const uint4*>(xt_l + bofs[ti] + poff));
        }
      }
      // product-major phases: hh, h*lo_x, lo_w*h  (uses cur_*)
#pragma unroll
      for (int ti = 0; ti < 4; ++ti) if (act[ti])
#pragma unroll
        for (int cot = 0; cot < 4; ++cot)
          acc[ti][cot] = __builtin_amdgcn_mfma_f32_16x16x32_bf16(cur_h[cot], bh[ti], acc[ti][cot], 0, 0, 0);
#pragma unroll
      for (int ti = 0; ti < 4; ++ti) if (act[ti])
#pragma unroll
        for (int cot = 0; cot < 4; ++cot)
          acc[ti][cot] = __builtin_amdgcn_mfma_f32_16x16x32_bf16(cur_h[cot], bl[ti], acc[ti][cot], 0, 0, 0);
#pragma unroll
      for (int ti = 0; ti < 4; ++ti) if (act[ti])
#pragma unroll
        for (int cot = 0; cot < 4; ++cot)
          acc[ti][cot] = __builtin_amdgcn_mfma_f32_16x16x32_bf16(cur_l[cot], bh[ti], acc[ti][cot], 0, 0, 0);
      if (p < 24) {
#pragma unroll
        for (int cot = 0; cot < 4; ++cot) { cur_h[cot] = nxt_h[cot]; cur_l[cot] = nxt_l[cot]; }
      }
    }
  }
#pragma unroll
  for (int cot = 0; cot < 4; ++cot) {
    const int co = cg * 64 + cot * 16 + fq * 4;
    const float4 bi = *reinterpret_cast<const float4*>(bias + co);
    const float bia[4] = {bi.x, bi.y, bi.z, bi.w};
#pragma unroll
    for (int ti = 0; ti < 4; ++ti) {
      const int tile = ti * 4 + wv;
      if (tile > 12) continue;
      const int n = tile * 16 + fr;
      if (n > 195) continue;
      const int oh = rg * 7 + n / 28, ow = n % 28;
      unsigned short h[4], l[4];
#pragma unroll
      for (int r = 0; r < 4; ++r) {
        const float v = fmaxf(acc[ti][cot][r] + bia[r], 0.f);
        bf16split(v, h[r], l[r]);
      }
      const size_t g = ((size_t)b * 784 + oh * 28 + ow) * 192 + co;
      *reinterpret_cast<uint2*>(yh + g) =
          make_uint2((unsigned)h[0] | ((unsigned)h[1] << 16),
                     (unsigned)h[2] | ((unsigned)h[3] << 16));
      *reinterpret_cast<uint2*>(yl + g) =
          make_uint2((unsigned)l[0] | ((unsigned)l[1] << 16),
                     (unsigned)l[2] | ((unsigned)l[3] << 16));
    }
  }
}

// ---------------- pool2 (vectorized): Y2 hi/lo [b][784][192] -> X3 [b][169][192]
__global__ __launch_bounds__(256) void pool2_hl_kernel(
    const unsigned short* __restrict__ yh, const unsigned short* __restrict__ yl,
    unsigned short* __restrict__ xh, unsigned short* __restrict__ xl) {
  const int tid = blockIdx.x * 256 + threadIdx.x;
  if (tid >= 128 * 169 * 48) return;
  const int c4 = tid % 48;
  const int r = tid / 48;
  const int s = r % 169;
  const int b = r / 169;
  const int oh = s / 13, ow = s % 13;
  float m[4] = {-INFINITY, -INFINITY, -INFINITY, -INFINITY};
#pragma unroll
  for (int kh = 0; kh < 3; ++kh) {
#pragma unroll
    for (int kw = 0; kw < 3; ++kw) {
      const int si = (oh * 2 + kh) * 28 + (ow * 2 + kw);
      const size_t g = ((size_t)b * 784 + si) * 192 + c4 * 4;
      const uint2 vh = *reinterpret_cast<const uint2*>(yh + g);
      const uint2 vl = *reinterpret_cast<const uint2*>(yl + g);
      const unsigned hw[2] = {vh.x, vh.y}, lw[2] = {vl.x, vl.y};
#pragma unroll
      for (int j = 0; j < 4; ++j) {
        const float v = bf2f((unsigned short)(hw[j >> 1] >> ((j & 1) * 16))) +
                        bf2f((unsigned short)(lw[j >> 1] >> ((j & 1) * 16)));
        m[j] = fmaxf(m[j], v);
      }
    }
  }
  unsigned short h[4], l[4];
#pragma unroll
  for (int j = 0; j < 4; ++j) bf16split(m[j], h[j], l[j]);
  const size_t gd = ((size_t)b * 169 + s) * 192 + c4 * 4;
  *reinterpret_cast<uint2*>(xh + gd) =
      make_uint2((unsigned)h[0] | ((unsigned)h[1] << 16),
                 (unsigned)h[2] | ((unsigned)h[3] << 16));
  *reinterpret_cast<uint2*>(xl + gd) =
      make_uint2((unsigned)l[0] | ((unsigned)l[1] << 16),
                 (unsigned)l[2] | ((unsigned)l[3] << 16));
}

// ---------------- conv3/4/5 MFMA: coalesced frag weights
__global__ __launch_bounds__(256, 4) void conv13_mfma_kernel(
    const unsigned short* __restrict__ xh, const unsigned short* __restrict__ xl,
    const unsigned short* __restrict__ wh, const unsigned short* __restrict__ wl,
    const float* __restrict__ bias,
    unsigned short* __restrict__ yh, unsigned short* __restrict__ yl,
    int C_in, int C_out) {
  __shared__ unsigned short xt_h[225 * 40];
  __shared__ unsigned short xt_l[225 * 40];
  const int t = threadIdx.x;
  const int lane = t & 63;
  const int wv = t >> 6;
  const int b = blockIdx.x;
  const int co0 = blockIdx.y * 64 + wv * 16;
  const int ctile = blockIdx.y * 4 + wv;
  const int fr = lane & 15;
  const int fq = lane >> 4;
  const int k0 = fq * 8;
  const int frag = fr * 32 + k0;

  int bofs[11];
#pragma unroll
  for (int nt = 0; nt < 11; ++nt) {
    int n = nt * 16 + fr;
    if (n > 168) n = 168;
    const int oh = n / 13, ow = n % 13;
    bofs[nt] = (oh * 15 + ow) * 40 + k0;
  }

  f32x4 acc[11];
#pragma unroll
  for (int nt = 0; nt < 11; ++nt) acc[nt] = (f32x4){0.f, 0.f, 0.f, 0.f};

  const int ncc = C_in >> 5;
  for (int cc = 0; cc < ncc; ++cc) {
    __syncthreads();
    for (int e = t; e < 900; e += 256) {
      const int sp = e >> 2, kg = e & 3;
      const int r = sp / 15, c = sp % 15;
      const int ir = r - 1, ic = c - 1;
      uint4 vh = make_uint4(0, 0, 0, 0), vl = make_uint4(0, 0, 0, 0);
      if (ir >= 0 && ir < 13 && ic >= 0 && ic < 13) {
        const size_t g = ((size_t)b * 169 + ir * 13 + ic) * C_in + cc * 32 + kg * 8;
        vh = *reinterpret_cast<const uint4*>(xh + g);
        vl = *reinterpret_cast<const uint4*>(xl + g);
      }
      *reinterpret_cast<uint4*>(xt_h + sp * 40 + kg * 8) = vh;
      *reinterpret_cast<uint4*>(xt_l + sp * 40 + kg * 8) = vl;
    }
    __syncthreads();
#pragma unroll
    for (int p = 0; p < 9; ++p) {
      // wt layout: [ctile][p][cc][16co][32ci]
      const size_t wg = ((((size_t)ctile * 9 + p) * ncc + cc) << 9) + frag;
      const bf16x8 ca_h = __builtin_bit_cast(bf16x8, *reinterpret_cast<const uint4*>(wh + wg));
      const bf16x8 ca_l = __builtin_bit_cast(bf16x8, *reinterpret_cast<const uint4*>(wl + wg));
      const int poff = ((p / 3) * 15 + (p % 3)) * 40;
#pragma unroll
      for (int q = 0; q < 3; ++q) {
        const int nq = (q < 2) ? 4 : 3;
        bf16x8 bh[4], bl[4];
#pragma unroll
        for (int i = 0; i < 4; ++i) {
          if (i < nq) {
            bh[i] = __builtin_bit_cast(bf16x8,
                *reinterpret_cast<const uint4*>(xt_h + bofs[q * 4 + i] + poff));
            bl[i] = __builtin_bit_cast(bf16x8,
                *reinterpret_cast<const uint4*>(xt_l + bofs[q * 4 + i] + poff));
          }
        }
#pragma unroll
        for (int i = 0; i < 4; ++i) if (i < nq)
          acc[q * 4 + i] = __builtin_amdgcn_mfma_f32_16x16x32_bf16(ca_h, bh[i], acc[q * 4 + i], 0, 0, 0);
#pragma unroll
        for (int i = 0; i < 4; ++i) if (i < nq)
          acc[q * 4 + i] = __builtin_amdgcn_mfma_f32_16x16x32_bf16(ca_h, bl[i], acc[q * 4 + i], 0, 0, 0);
#pragma unroll
        for (int i = 0; i < 4; ++i) if (i < nq)
          acc[q * 4 + i] = __builtin_amdgcn_mfma_f32_16x16x32_bf16(ca_l, bh[i], acc[q * 4 + i], 0, 0, 0);
      }
    }
  }
  const int co_w = co0 + fq * 4;
  const float4 bi = *reinterpret_cast<const float4*>(bias + co_w);
  const float bia[4] = {bi.x, bi.y, bi.z, bi.w};
#pragma unroll
  for (int nt = 0; nt < 11; ++nt) {
    const int n = nt * 16 + fr;
    if (n > 168) continue;
    unsigned short h[4], l[4];
#pragma unroll
    for (int r = 0; r < 4; ++r) {
      float v = fmaxf(acc[nt][r] + bia[r], 0.f);
      bf16split(v, h[r], l[r]);
    }
    const size_t g = ((size_t)b * 169 + n) * C_out + co_w;
    *reinterpret_cast<uint2*>(yh + g) =
        make_uint2((unsigned)h[0] | ((unsigned)h[1] << 16),
                   (unsigned)h[2] | ((unsigned)h[3] << 16));
    *reinterpret_cast<uint2*>(yl + g) =
        make_uint2((unsigned)l[0] | ((unsigned)l[1] << 16),
                   (unsigned)l[2] | ((unsigned)l[3] << 16));
  }
}

// ---------------- pool3: Y5 hi/lo [b][169][256] -> fp32 [b][256][6][6]
__global__ __launch_bounds__(256) void pool3_hl_kernel(
    const unsigned short* __restrict__ yh, const unsigned short* __restrict__ yl,
    float* __restrict__ out) {
  const int b = blockIdx.x;
  const int s2 = blockIdx.y;
  const int c = threadIdx.x;
  const int oh = s2 / 6, ow = s2 % 6;
  float m = -INFINITY;
#pragma unroll
  for (int kh = 0; kh < 3; ++kh)
#pragma unroll
    for (int kw = 0; kw < 3; ++kw) {
      const int si = (oh * 2 + kh) * 13 + (ow * 2 + kw);
      const size_t g = ((size_t)b * 169 + si) * 256 + c;
      m = fmaxf(m, bf2f(yh[g]) + bf2f(yl[g]));
    }
  out[((size_t)b * 256 + c) * 36 + s2] = m;
}

// ---------------- fc1/fc2 MFMA: reg-split weights, nt-pair product-major
__global__ __launch_bounds__(256, 2) void fc_mfma_kernel(
    const float* __restrict__ act, const float* __restrict__ Wm,
    float* __restrict__ part, int K, int kchunk, int Cout) {
  __shared__ unsigned short ah[128 * 40];
  __shared__ unsigned short al[128 * 40];
  const int t = threadIdx.x;
  const int lane = t & 63, wv = t >> 6;
  const int m0 = blockIdx.x * 128 + wv * 32;
  const int kb = blockIdx.y * kchunk;
  const int fr = lane & 15, fq = lane >> 4;

  f32x4 acc[2][8];
#pragma unroll
  for (int i = 0; i < 2; ++i)
#pragma unroll
    for (int j = 0; j < 8; ++j) acc[i][j] = (f32x4){0.f, 0.f, 0.f, 0.f};

  for (int kc = kb; kc < kb + kchunk; kc += 32) {
    __syncthreads();
#pragma unroll
    for (int i = 0; i < 4; ++i) {
      const int u = t + i * 256;
      const int n = u >> 3, j = u & 7;
      const float4 v = *reinterpret_cast<const float4*>(act + (size_t)n * K + kc + j * 4);
      const float vv[4] = {v.x, v.y, v.z, v.w};
      unsigned short h[4], l[4];
#pragma unroll
      for (int q = 0; q < 4; ++q) bf16split_fast(vv[q], h[q], l[q]);
      *reinterpret_cast<uint2*>(ah + n * 40 + j * 4) =
          make_uint2((unsigned)h[0] | ((unsigned)h[1] << 16),
                     (unsigned)h[2] | ((unsigned)h[3] << 16));
      *reinterpret_cast<uint2*>(al + n * 40 + j * 4) =
          make_uint2((unsigned)l[0] | ((unsigned)l[1] << 16),
                     (unsigned)l[2] | ((unsigned)l[3] << 16));
    }
    __syncthreads();
    bf16x8 a_h[2], a_l[2];
#pragma unroll
    for (int mt = 0; mt < 2; ++mt) {
      const float* wp = Wm + (size_t)(m0 + mt * 16 + fr) * K + kc + fq * 8;
      const float4 w0 = *reinterpret_cast<const float4*>(wp);
      const float4 w1 = *reinterpret_cast<const float4*>(wp + 4);
      const float ws[8] = {w0.x, w0.y, w0.z, w0.w, w1.x, w1.y, w1.z, w1.w};
#pragma unroll
      for (int q = 0; q < 8; ++q) {
        unsigned short h, l;
        bf16split_fast(ws[q], h, l);
        a_h[mt][q] = (short)h;
        a_l[mt][q] = (short)l;
      }
    }
#pragma unroll
    for (int np = 0; np < 4; ++np) {
      bf16x8 bh[2], bl[2];
#pragma unroll
      for (int i = 0; i < 2; ++i) {
        const int nt = np * 2 + i;
        bh[i] = __builtin_bit_cast(bf16x8,
            *reinterpret_cast<const uint4*>(ah + (nt * 16 + fr) * 40 + fq * 8));
        bl[i] = __builtin_bit_cast(bf16x8,
            *reinterpret_cast<const uint4*>(al + (nt * 16 + fr) * 40 + fq * 8));
      }
#pragma unroll
      for (int i = 0; i < 2; ++i)
#pragma unroll
        for (int mt = 0; mt < 2; ++mt)
          acc[mt][np * 2 + i] = __builtin_amdgcn_mfma_f32_16x16x32_bf16(a_h[mt], bh[i], acc[mt][np * 2 + i], 0, 0, 0);
#pragma unroll
      for (int i = 0; i < 2; ++i)
#pragma unroll
        for (int mt = 0; mt < 2; ++mt)
          acc[mt][np * 2 + i] = __builtin_amdgcn_mfma_f32_16x16x32_bf16(a_h[mt], bl[i], acc[mt][np * 2 + i], 0, 0, 0);
#pragma unroll
      for (int i = 0; i < 2; ++i)
#pragma unroll
        for (int mt = 0; mt < 2; ++mt)
          acc[mt][np * 2 + i] = __builtin_amdgcn_mfma_f32_16x16x32_bf16(a_l[mt], bh[i], acc[mt][np * 2 + i], 0, 0, 0);
    }
  }
  const size_t base = (size_t)blockIdx.y * Cout * 128;
#pragma unroll
  for (int mt = 0; mt < 2; ++mt) {
#pragma unroll
    for (int nt = 0; nt < 8; ++nt) {
#pragma unroll
      for (int r = 0; r < 4; ++r) {
        const int m = m0 + mt * 16 + fq * 4 + r;
        const int n = nt * 16 + fr;
        part[base + (size_t)m * 128 + n] = acc[mt][nt][r];
      }
    }
  }
}

// ---------------- fc reduce: sum KS partials, +bias, relu, transpose to [n][Cout]
__global__ __launch_bounds__(256) void fc_reduce_kernel(
    const float* __restrict__ part, const float* __restrict__ bias,
    float* __restrict__ out, int Cout, int KS, int relu) {
  const int g = blockIdx.x * 256 + threadIdx.x;
  if (g >= Cout * 128) return;
  const int n = g & 127, m = g >> 7;
  float s = 0.f;
  for (int ks = 0; ks < KS; ++ks)
    s += part[(size_t)ks * Cout * 128 + (size_t)m * 128 + n];
  s += bias[m];
  if (relu) s = fmaxf(s, 0.f);
  out[(size_t)n * Cout + m] = s;
}

// ---------------- fc3: logits[128,10]
__global__ __launch_bounds__(256) void fc3_kernel(
    const float* __restrict__ A, const float* __restrict__ W,
    const float* __restrict__ bias, float* __restrict__ out) {
  __shared__ float red[256];
  const int b = blockIdx.x;
  const int t = threadIdx.x;
  float acc[10];
#pragma unroll
  for (int n = 0; n < 10; ++n) acc[n] = 0.f;
  const float* a = A + (size_t)b * 4096;
  for (int k = t; k < 4096; k += 256) {
    const float av = a[k];
#pragma unroll
    for (int n = 0; n < 10; ++n) acc[n] = fmaf(av, W[n * 4096 + k], acc[n]);
  }
  for (int n = 0; n < 10; ++n) {
    red[t] = acc[n];
    __syncthreads();
    for (int off = 128; off > 0; off >>= 1) {
      if (t < off) red[t] += red[t + off];
      __syncthreads();
    }
    if (t == 0) out[b * 10 + n] = red[0] + bias[n];
    __syncthreads();
  }
}

// ---------------- post
__global__ void post_kernel(const float* __restrict__ logits,
                            const float* __restrict__ unif,
                            const float* __restrict__ noise,
                            float* __restrict__ out) {
  const int b = blockIdx.x * blockDim.x + threadIdx.x;
  if (b >= 128) return;
  float lg[10];
#pragma unroll
  for (int j = 0; j < 10; ++j) lg[j] = logits[b * 10 + j];
  float m = lg[0];
  int idx = 0;
#pragma unroll
  for (int j = 1; j < 10; ++j) {
    if (lg[j] > m) { m = lg[j]; idx = j; }
  }
  float v[10];
#pragma unroll
  for (int j = 0; j < 10; ++j)
    v[j] = ((j == idx) ? lg[j] : unif[b * 10 + j] * m) + noise[b * 10 + j];
  float mx = v[0];
#pragma unroll
  for (int j = 1; j < 10; ++j) mx = fmaxf(mx, v[j]);
  float sum = 0.f;
#pragma unroll
  for (int j = 0; j < 10; ++j) { v[j] = expf(v[j] - mx); sum += v[j]; }
  const float inv = 1.f / sum;
#pragma unroll
  for (int j = 0; j < 10; ++j) out[b * 10 + j] = v[j] * inv;
}

// ---------------------------------------------------------------------------
extern "C" void kernel_launch(void* const* d_in, const int* in_sizes, int n_in,
                              void* d_out, int out_size, void* d_ws, size_t ws_size,
                              hipStream_t stream) {
  const float* x     = (const float*)d_in[0];
  const float* w1    = (const float*)d_in[1];
  const float* b1    = (const float*)d_in[2];
  const float* w2    = (const float*)d_in[3];
  const float* b2    = (const float*)d_in[4];
  const float* w3    = (const float*)d_in[5];
  const float* b3    = (const float*)d_in[6];
  const float* w4    = (const float*)d_in[7];
  const float* b4    = (const float*)d_in[8];
  const float* w5    = (const float*)d_in[9];
  const float* b5    = (const float*)d_in[10];
  const float* fc1_w = (const float*)d_in[11];
  const float* fc1_b = (const float*)d_in[12];
  const float* fc2_w = (const float*)d_in[13];
  const float* fc2_b = (const float*)d_in[14];
  const float* fc3_w = (const float*)d_in[15];
  const float* fc3_b = (const float*)d_in[16];
  const float* unif  = (const float*)d_in[17];
  const float* noise = (const float*)d_in[18];
  float* out = (float*)d_out;

  char* W = (char*)d_ws;
#define FP(off) ((float*)(W + (off)))
#define US(off) ((unsigned short*)(W + (off)))

  // conv1 -> fp32 [128,64,57,57] at OFF_C1O
  conv1_kernel<<<dim3(13, 128), 256, 0, stream>>>(x, w1, b1, FP(OFF_C1O));
  // fused pool1+convert -> X2 hi/lo [b][784][64]
  pool1cvt_kernel<<<392, 256, 0, stream>>>(FP(OFF_C1O), US(OFF_X2H), US(OFF_X2L));
  // weight transforms (fragment layout)
  wtrans_hl_kernel<<<512, 256, 0, stream>>>(w2, US(OFF_WT2H), US(OFF_WT2L), 64, 25, 192);
  wtrans_hl_kernel<<<512, 256, 0, stream>>>(w3, US(OFF_WT3H), US(OFF_WT3L), 192, 9, 384);
  wtrans_hl_kernel<<<512, 256, 0, stream>>>(w4, US(OFF_WT4H), US(OFF_WT4L), 384, 9, 256);
  wtrans_hl_kernel<<<512, 256, 0, stream>>>(w5, US(OFF_WT5H), US(OFF_WT5L), 256, 9, 256);
  // conv2 -> Y2 hi/lo [b][784][192]
  conv2_mfma_kernel<<<dim3(128, 4, 3), 256, 0, stream>>>(
      US(OFF_X2H), US(OFF_X2L), US(OFF_WT2H), US(OFF_WT2L), b2,
      US(OFF_Y2H), US(OFF_Y2L));
  // pool2 -> X3 hi/lo [b][169][192]
  pool2_hl_kernel<<<4056, 256, 0, stream>>>(
      US(OFF_Y2H), US(OFF_Y2L), US(OFF_X3H), US(OFF_X3L));
  // conv3 -> Y3 [b][169][384]
  conv13_mfma_kernel<<<dim3(128, 6), 256, 0, stream>>>(
      US(OFF_X3H), US(OFF_X3L), US(OFF_WT3H), US(OFF_WT3L), b3,
      US(OFF_Y3H), US(OFF_Y3L), 192, 384);
  // conv4 -> Y4 [b][169][256]
  conv13_mfma_kernel<<<dim3(128, 4), 256, 0, stream>>>(
      US(OFF_Y3H), US(OFF_Y3L), US(OFF_WT4H), US(OFF_WT4L), b4,
      US(OFF_Y4H), US(OFF_Y4L), 384, 256);
  // conv5 -> Y5 [b][169][256]
  conv13_mfma_kernel<<<dim3(128, 4), 256, 0, stream>>>(
      US(OFF_Y4H), US(OFF_Y4L), US(OFF_WT5H), US(OFF_WT5L), b5,
      US(OFF_Y5H), US(OFF_Y5L), 256, 256);
  // pool3 -> P3 fp32 [128][9216]
  pool3_hl_kernel<<<dim3(128, 36), 256, 0, stream>>>(US(OFF_Y5H), US(OFF_Y5L), FP(OFF_P3));
  // fc1/fc2
  fc_mfma_kernel<<<dim3(32, 16), 256, 0, stream>>>(FP(OFF_P3), fc1_w, FP(OFF_PART), 9216, 576, 4096);
  fc_reduce_kernel<<<2048, 256, 0, stream>>>(FP(OFF_PART), fc1_b, FP(OFF_FC1), 4096, 16, 1);
  fc_mfma_kernel<<<dim3(32, 16), 256, 0, stream>>>(FP(OFF_FC1), fc2_w, FP(OFF_PART), 4096, 256, 4096);
  fc_reduce_kernel<<<2048, 256, 0, stream>>>(FP(OFF_PART), fc2_b, FP(OFF_FC2), 4096, 16, 1);
  // fc3 + post
  fc3_kernel<<<128, 256, 0, stream>>>(FP(OFF_FC2), fc3_w, fc3_b, FP(OFF_LOG));
  post_kernel<<<1, 128, 0, stream>>>(FP(OFF_LOG), unif, noise, out);
}